// Round 10
// baseline (231.626 us; speedup 1.0000x reference)
//
#include <hip/hip_runtime.h>
#include <cfloat>
#include <cmath>

// Problem constants
#define NB 32           // B
#define NN 8            // N codebooks
#define NM 512          // M codes
#define ND 32           // D dim
#define NHW 1024        // H*W
#define NC 256          // C = N*D
#define NCHW (NC * NHW) // 262144
#define NL (NB * NHW)   // 32768 points per codebook
#define EPAD 40         // padded bf16 row (80 B)
#define XPAD 33         // padded fp32 row for x / dw staging
#define TSTR (16 * EPAD) // shorts per 16-code tile

static constexpr float DECAYF = (float)0.999;
static constexpr float OMDF = (float)(1.0 - 0.999);
static constexpr float EPSF = 1e-5f;
static constexpr float MEPSF = (float)(512.0 * 1e-5);
static constexpr float LOSS_SCALE = (float)(0.25 / 8388608.0);

// Output layout (floats)
#define OUT_LOSS (NB * NC * NHW)         // 8388608
#define OUT_PERP (OUT_LOSS + 1)
#define OUT_EMB (OUT_PERP + 1)
#define OUT_CNT (OUT_EMB + NN * NM * ND)
#define OUT_W (OUT_CNT + NN * NM)

typedef __attribute__((ext_vector_type(8))) short bf16x8;
typedef __attribute__((ext_vector_type(4))) float f32x4;

__device__ inline unsigned short f2bf(float f) {
    unsigned u = __builtin_bit_cast(unsigned, f);
    u += 0x7FFFu + ((u >> 16) & 1u);
    return (unsigned short)(u >> 16);
}
__device__ inline float bf2f(unsigned short h) {
    unsigned u = ((unsigned)h) << 16;
    return __builtin_bit_cast(float, u);
}

// ---- K1: embedding prep: bf16 hi/lo split (padded rows) + e2 ----
__global__ void e_prep(const float* __restrict__ emb, unsigned short* __restrict__ ehi,
                       unsigned short* __restrict__ elo, float* __restrict__ e2) {
    const int i = blockIdx.x * 256 + threadIdx.x; // (n*512 + m), 4096 total
    const float* e = emb + i * ND;
    unsigned short* hi = ehi + (size_t)i * EPAD;
    unsigned short* lo = elo + (size_t)i * EPAD;
    float s = 0.f;
#pragma unroll
    for (int d = 0; d < ND; ++d) {
        const float v = e[d];
        s = fmaf(v, v, s);
        const unsigned short h = f2bf(v);
        hi[d] = h;
        lo[d] = f2bf(v - bf2f(h));
    }
    e2[i] = s;
}

// ---- K2: MFMA distances + argmin + quantized output + loss ----
// Codes read as B-fragments from global (L2-resident); 2 m-tiles per
// iteration with pair prefetch (effective 2-deep) to cover L2 latency.
__launch_bounds__(256, 4)
__global__ void vq_argmin(const float* __restrict__ x,
                          const unsigned short* __restrict__ ehi,
                          const unsigned short* __restrict__ elo,
                          const float* __restrict__ e2g,
                          const float* __restrict__ emb,
                          float* __restrict__ out,
                          unsigned short* __restrict__ idx_out,
                          float* __restrict__ loss_out) {
    __shared__ __align__(16) float sx[256 * XPAD];           // 33792 B
    __shared__ float se2[NM];                                // 2048 B
    __shared__ unsigned short sidx[256];
    __shared__ float red[4];

    const int n = blockIdx.y;
    const int lbase = blockIdx.x * 256;
    const int tid = threadIdx.x;
    const int b = lbase >> 10;
    const int hw0 = lbase & (NHW - 1);

    // stage x tile: [256 points][32 d] fp32, padded (bank-conflict-free writes)
    {
        const float* xp = x + (size_t)b * NCHW + n * ND * NHW + hw0 + tid;
#pragma unroll
        for (int d = 0; d < ND; ++d)
            sx[tid * XPAD + d] = xp[d * NHW];
    }
    for (int i = tid; i < NM; i += 256) se2[i] = e2g[n * NM + i];
    __syncthreads();

    const int lane = tid & 63;
    const int w = tid >> 6;
    const int j16 = lane & 15;   // row (A) / col (B) index
    const int kg = lane >> 4;    // k-group

    // A fragments: 4 ltiles x 8 bf16, hi/lo split
    bf16x8 ah[4], al[4];
#pragma unroll
    for (int lt = 0; lt < 4; ++lt) {
        const int row = w * 64 + lt * 16 + j16;
        const float* sr = &sx[row * XPAD + kg * 8];
#pragma unroll
        for (int j = 0; j < 8; ++j) {
            const float v = sr[j];
            const unsigned short h = f2bf(v);
            ah[lt][j] = (short)h;
            al[lt][j] = (short)f2bf(v - bf2f(h));
        }
    }

    float bd[4][4];
    int bm[4][4];
#pragma unroll
    for (int lt = 0; lt < 4; ++lt)
#pragma unroll
        for (int r = 0; r < 4; ++r) { bd[lt][r] = FLT_MAX; bm[lt][r] = 0; }

    // B-fragment base for this lane: code row (n*512 + j16), d-slice kg*8
    const unsigned short* bh_base = ehi + ((size_t)n * NM + j16) * EPAD + kg * 8;
    const unsigned short* bl_base = elo + ((size_t)n * NM + j16) * EPAD + kg * 8;

    // 2 tiles per iteration, pair prefetch (2-deep effective)
    bf16x8 bh0 = *(const bf16x8*)(bh_base);
    bf16x8 bl0 = *(const bf16x8*)(bl_base);
    bf16x8 bh1 = *(const bf16x8*)(bh_base + TSTR);
    bf16x8 bl1 = *(const bf16x8*)(bl_base + TSTR);
    for (int mt = 0; mt < 32; mt += 2) {
        const bf16x8 cbh0 = bh0, cbl0 = bl0, cbh1 = bh1, cbl1 = bl1;
        if (mt < 30) {
            bh0 = *(const bf16x8*)(bh_base + (size_t)(mt + 2) * TSTR);
            bl0 = *(const bf16x8*)(bl_base + (size_t)(mt + 2) * TSTR);
            bh1 = *(const bf16x8*)(bh_base + (size_t)(mt + 3) * TSTR);
            bl1 = *(const bf16x8*)(bl_base + (size_t)(mt + 3) * TSTR);
        }
        {
            const int mloc = mt * 16 + j16;
            const float e2v = se2[mloc];
#pragma unroll
            for (int lt = 0; lt < 4; ++lt) {
                f32x4 c = {0.f, 0.f, 0.f, 0.f};
                c = __builtin_amdgcn_mfma_f32_16x16x32_bf16(ah[lt], cbh0, c, 0, 0, 0);
                c = __builtin_amdgcn_mfma_f32_16x16x32_bf16(al[lt], cbh0, c, 0, 0, 0);
                c = __builtin_amdgcn_mfma_f32_16x16x32_bf16(ah[lt], cbl0, c, 0, 0, 0);
#pragma unroll
                for (int r = 0; r < 4; ++r) {
                    const float dist = fmaf(-2.f, c[r], e2v);
                    if (dist < bd[lt][r]) { bd[lt][r] = dist; bm[lt][r] = mloc; }
                }
            }
        }
        {
            const int mloc = (mt + 1) * 16 + j16;
            const float e2v = se2[mloc];
#pragma unroll
            for (int lt = 0; lt < 4; ++lt) {
                f32x4 c = {0.f, 0.f, 0.f, 0.f};
                c = __builtin_amdgcn_mfma_f32_16x16x32_bf16(ah[lt], cbh1, c, 0, 0, 0);
                c = __builtin_amdgcn_mfma_f32_16x16x32_bf16(al[lt], cbh1, c, 0, 0, 0);
                c = __builtin_amdgcn_mfma_f32_16x16x32_bf16(ah[lt], cbl1, c, 0, 0, 0);
#pragma unroll
                for (int r = 0; r < 4; ++r) {
                    const float dist = fmaf(-2.f, c[r], e2v);
                    if (dist < bd[lt][r]) { bd[lt][r] = dist; bm[lt][r] = mloc; }
                }
            }
        }
    }

    // reduce over the 16 lanes (cols) of each group; tie -> lower m (np.argmin)
#pragma unroll
    for (int lt = 0; lt < 4; ++lt)
#pragma unroll
        for (int r = 0; r < 4; ++r) {
            float d0 = bd[lt][r];
            int m0 = bm[lt][r];
#pragma unroll
            for (int off = 1; off < 16; off <<= 1) {
                const float dn = __shfl_xor(d0, off, 64);
                const int mn = __shfl_xor(m0, off, 64);
                if (dn < d0 || (dn == d0 && mn < m0)) { d0 = dn; m0 = mn; }
            }
            bd[lt][r] = d0;
            bm[lt][r] = m0;
        }
    if (j16 == 0) {
#pragma unroll
        for (int lt = 0; lt < 4; ++lt)
#pragma unroll
            for (int r = 0; r < 4; ++r)
                sidx[w * 64 + lt * 16 + kg * 4 + r] = (unsigned short)bm[lt][r];
    }
    __syncthreads();

    // epilogue: idx write, quantized out, exact fp32 loss
    const unsigned m = sidx[tid];
    idx_out[n * NL + lbase + tid] = (unsigned short)m;
    const float* q = emb + ((size_t)n * NM + m) * ND;
    float* op = out + (size_t)b * NCHW + n * ND * NHW + hw0 + tid;
    float lacc = 0.f;
#pragma unroll
    for (int d0 = 0; d0 < ND; d0 += 4) {
        const float4 qv = *(const float4*)&q[d0];
        float xd, df;
        xd = sx[tid * XPAD + d0 + 0]; op[(d0 + 0) * NHW] = qv.x; df = xd - qv.x; lacc = fmaf(df, df, lacc);
        xd = sx[tid * XPAD + d0 + 1]; op[(d0 + 1) * NHW] = qv.y; df = xd - qv.y; lacc = fmaf(df, df, lacc);
        xd = sx[tid * XPAD + d0 + 2]; op[(d0 + 2) * NHW] = qv.z; df = xd - qv.z; lacc = fmaf(df, df, lacc);
        xd = sx[tid * XPAD + d0 + 3]; op[(d0 + 3) * NHW] = qv.w; df = xd - qv.w; lacc = fmaf(df, df, lacc);
    }
#pragma unroll
    for (int off = 32; off; off >>= 1) lacc += __shfl_down(lacc, off);
    if (lane == 0) red[w] = lacc;
    __syncthreads();
    if (tid == 0)
        atomicAdd(loss_out, (red[0] + red[1] + red[2] + red[3]) * LOSS_SCALE);
}

// ---- K3: counts/dw scatter: LDS accumulate over bpc batches; flush is
//      PLAIN STORES into this block's exclusive (copy,n) partial buffer
//      (exclusive=1), or atomicAdd fallback into copy 0 (exclusive=0). ----
__launch_bounds__(1024, 1)
__global__ void vq_scatter(const float* __restrict__ x,
                           const unsigned short* __restrict__ idx,
                           float* __restrict__ pdw, float* __restrict__ pcnt,
                           int bpc, int exclusive) {
    __shared__ float sdw[NM * XPAD]; // 67584 B
    __shared__ float scnt[NM];
    const int n = blockIdx.y;
    const int ch = blockIdx.x; // chunk of bpc batches
    const int tid = threadIdx.x; // 0..1023 == hw

    for (int i = tid; i < NM * XPAD; i += 1024) sdw[i] = 0.f;
    if (tid < NM) scnt[tid] = 0.f;
    __syncthreads();

    for (int bb = 0; bb < bpc; ++bb) {
        const int b = ch * bpc + bb;
        const unsigned m = idx[n * NL + b * NHW + tid];
        const float* xp = x + (size_t)b * NCHW + n * ND * NHW;
        float* dst = &sdw[m * XPAD];
#pragma unroll
        for (int d = 0; d < ND; ++d)
            atomicAdd(&dst[d], xp[d * NHW + tid]);
        atomicAdd(&scnt[m], 1.0f);
    }
    __syncthreads();

    const int c = exclusive ? ch : 0;
    float* dwn = pdw + (size_t)c * (NN * NM * ND) + (size_t)n * NM * ND;
    if (exclusive) {
        for (int i = tid; i < NM * ND; i += 1024)
            dwn[i] = sdw[(i >> 5) * XPAD + (i & 31)];
        if (tid < NM) pcnt[(size_t)c * (NN * NM) + n * NM + tid] = scnt[tid];
    } else {
        for (int i = tid; i < NM * ND; i += 1024)
            atomicAdd(&dwn[i], sdw[(i >> 5) * XPAD + (i & 31)]);
        if (tid < NM) atomicAdd(&pcnt[n * NM + tid], scnt[tid]);
    }
}

// ---- K4a: reduce copies + EMA count update + perplexity ----
__global__ void vq_update_cnt(const float* __restrict__ ema_count,
                              const float* __restrict__ pcnt,
                              float* __restrict__ out_cnt,
                              float* __restrict__ perp_out, int copies) {
    const int n = blockIdx.x;
    const int m = threadIdx.x; // 512
    __shared__ float r1[8], r2[8];
    __shared__ float s_ntot;

    float cnt = 0.f;
    for (int c = 0; c < copies; ++c)
        cnt += pcnt[(size_t)c * (NN * NM) + n * NM + m];

    const float cnew = DECAYF * ema_count[n * NM + m] + OMDF * cnt;
    const float avg = cnt / (float)NL;
    const float pterm = avg * logf(avg + 1e-10f);

    float v1 = cnew, v2 = pterm;
#pragma unroll
    for (int off = 32; off; off >>= 1) {
        v1 += __shfl_down(v1, off);
        v2 += __shfl_down(v2, off);
    }
    if ((m & 63) == 0) { r1[m >> 6] = v1; r2[m >> 6] = v2; }
    __syncthreads();
    if (m == 0) {
        float a = 0.f, bsum = 0.f;
#pragma unroll
        for (int i = 0; i < 8; ++i) { a += r1[i]; bsum += r2[i]; }
        s_ntot = a;
        atomicAdd(perp_out, expf(-bsum));
    }
    __syncthreads();
    const float ntot = s_ntot;
    out_cnt[n * NM + m] = (cnew + EPSF) / (ntot + MEPSF) * ntot;
}

// ---- K4b: reduce copies + EMA weight + embedding_new ----
__global__ void vq_update_w(const float* __restrict__ ema_weight,
                            const float* __restrict__ pdw,
                            const float* __restrict__ out_cnt,
                            float* __restrict__ out_w,
                            float* __restrict__ out_emb, int copies) {
    const int i = blockIdx.x * 512 + threadIdx.x; // 131072
    float dw = 0.f;
    for (int c = 0; c < copies; ++c)
        dw += pdw[(size_t)c * (NN * NM * ND) + i];
    const float wnew = DECAYF * ema_weight[i] + OMDF * dw;
    out_w[i] = wnew;
    out_emb[i] = wnew / out_cnt[i >> 5];
}

extern "C" void kernel_launch(void* const* d_in, const int* in_sizes, int n_in,
                              void* d_out, int out_size, void* d_ws, size_t ws_size,
                              hipStream_t stream) {
    const float* x = (const float*)d_in[0];
    const float* emb = (const float*)d_in[1];
    const float* ema_count = (const float*)d_in[2];
    const float* ema_weight = (const float*)d_in[3];
    float* out = (float*)d_out;
    char* ws = (char*)d_ws;

    // choose partial-copy count from scratch size (ws_size is call-invariant)
    const size_t rest_bytes = 16384 + 327680 + 327680 + 524288; // e2, ehi, elo, idx
    const size_t per_copy = (size_t)(NN * NM + NN * NM * ND) * 4; // 540672
    int copies, bpc;
    if (ws_size >= 16 * per_copy + rest_bytes)      { copies = 16; bpc = 2; }
    else if (ws_size >= 8 * per_copy + rest_bytes)  { copies = 8;  bpc = 4; }
    else                                            { copies = 1;  bpc = 4; }
    const int exclusive = (copies > 1) ? 1 : 0;

    float* pcnt = (float*)ws;                                   // copies * 16384 B
    float* pdw = (float*)(ws + (size_t)copies * NN * NM * 4);   // copies * 524288 B
    char* restp = ws + (size_t)copies * per_copy;
    float* e2 = (float*)restp;
    unsigned short* ehi = (unsigned short*)(restp + 16384);
    unsigned short* elo = (unsigned short*)(restp + 16384 + 327680);
    unsigned short* idxp = (unsigned short*)(restp + 16384 + 655360);

    // zero accumulators only when the flush accumulates atomically;
    // exclusive mode overwrites every cell of every copy.
    if (!exclusive)
        hipMemsetAsync(ws, 0, per_copy, stream);
    hipMemsetAsync(out + OUT_LOSS, 0, 2 * sizeof(float), stream);

    e_prep<<<16, 256, 0, stream>>>(emb, ehi, elo, e2);
    vq_argmin<<<dim3(NL / 256, NN), 256, 0, stream>>>(x, ehi, elo, e2, emb, out, idxp,
                                                      out + OUT_LOSS);
    vq_scatter<<<dim3(NB / bpc, NN), 1024, 0, stream>>>(x, idxp, pdw, pcnt, bpc,
                                                        exclusive);
    vq_update_cnt<<<NN, NM, 0, stream>>>(ema_count, pcnt, out + OUT_CNT, out + OUT_PERP,
                                         copies);
    vq_update_w<<<NN * NM * ND / 512, 512, 0, stream>>>(ema_weight, pdw, out + OUT_CNT,
                                                        out + OUT_EMB, out + OUT_W, copies);
}

// Round 11
// 205.714 us; speedup vs baseline: 1.1260x; 1.1260x over previous
//
#include <hip/hip_runtime.h>
#include <cfloat>
#include <cmath>

// Problem constants
#define NB 32           // B
#define NN 8            // N codebooks
#define NM 512          // M codes
#define ND 32           // D dim
#define NHW 1024        // H*W
#define NC 256          // C = N*D
#define NCHW (NC * NHW) // 262144
#define NL (NB * NHW)   // 32768 points per codebook
#define EPAD 40         // padded bf16 row (80 B)
#define XPAD 33         // padded fp32 row for x / dw staging
#define TSTR (16 * EPAD) // shorts per 16-code tile
#define SCHUNK 128      // points per scatter staging chunk

static constexpr float DECAYF = (float)0.999;
static constexpr float OMDF = (float)(1.0 - 0.999);
static constexpr float EPSF = 1e-5f;
static constexpr float MEPSF = (float)(512.0 * 1e-5);
static constexpr float LOSS_SCALE = (float)(0.25 / 8388608.0);

// Output layout (floats)
#define OUT_LOSS (NB * NC * NHW)         // 8388608
#define OUT_PERP (OUT_LOSS + 1)
#define OUT_EMB (OUT_PERP + 1)
#define OUT_CNT (OUT_EMB + NN * NM * ND)
#define OUT_W (OUT_CNT + NN * NM)

typedef __attribute__((ext_vector_type(8))) short bf16x8;
typedef __attribute__((ext_vector_type(4))) float f32x4;

__device__ inline unsigned short f2bf(float f) {
    unsigned u = __builtin_bit_cast(unsigned, f);
    u += 0x7FFFu + ((u >> 16) & 1u);
    return (unsigned short)(u >> 16);
}
__device__ inline float bf2f(unsigned short h) {
    unsigned u = ((unsigned)h) << 16;
    return __builtin_bit_cast(float, u);
}

// ---- K1: embedding prep: bf16 hi/lo split (padded rows) + e2 ----
__global__ void e_prep(const float* __restrict__ emb, unsigned short* __restrict__ ehi,
                       unsigned short* __restrict__ elo, float* __restrict__ e2) {
    const int i = blockIdx.x * 256 + threadIdx.x; // (n*512 + m), 4096 total
    const float* e = emb + i * ND;
    unsigned short* hi = ehi + (size_t)i * EPAD;
    unsigned short* lo = elo + (size_t)i * EPAD;
    float s = 0.f;
#pragma unroll
    for (int d = 0; d < ND; ++d) {
        const float v = e[d];
        s = fmaf(v, v, s);
        const unsigned short h = f2bf(v);
        hi[d] = h;
        lo[d] = f2bf(v - bf2f(h));
    }
    e2[i] = s;
}

// ---- K2: MFMA distances + argmin + quantized output + loss ----
// (unchanged from round 9/10 for attribution)
__launch_bounds__(256, 4)
__global__ void vq_argmin(const float* __restrict__ x,
                          const unsigned short* __restrict__ ehi,
                          const unsigned short* __restrict__ elo,
                          const float* __restrict__ e2g,
                          const float* __restrict__ emb,
                          float* __restrict__ out,
                          unsigned short* __restrict__ idx_out,
                          float* __restrict__ loss_out) {
    __shared__ __align__(16) float sx[256 * XPAD];           // 33792 B
    __shared__ float se2[NM];                                // 2048 B
    __shared__ unsigned short sidx[256];
    __shared__ float red[4];

    const int n = blockIdx.y;
    const int lbase = blockIdx.x * 256;
    const int tid = threadIdx.x;
    const int b = lbase >> 10;
    const int hw0 = lbase & (NHW - 1);

    // stage x tile: [256 points][32 d] fp32, padded (bank-conflict-free writes)
    {
        const float* xp = x + (size_t)b * NCHW + n * ND * NHW + hw0 + tid;
#pragma unroll
        for (int d = 0; d < ND; ++d)
            sx[tid * XPAD + d] = xp[d * NHW];
    }
    for (int i = tid; i < NM; i += 256) se2[i] = e2g[n * NM + i];
    __syncthreads();

    const int lane = tid & 63;
    const int w = tid >> 6;
    const int j16 = lane & 15;   // row (A) / col (B) index
    const int kg = lane >> 4;    // k-group

    // A fragments: 4 ltiles x 8 bf16, hi/lo split
    bf16x8 ah[4], al[4];
#pragma unroll
    for (int lt = 0; lt < 4; ++lt) {
        const int row = w * 64 + lt * 16 + j16;
        const float* sr = &sx[row * XPAD + kg * 8];
#pragma unroll
        for (int j = 0; j < 8; ++j) {
            const float v = sr[j];
            const unsigned short h = f2bf(v);
            ah[lt][j] = (short)h;
            al[lt][j] = (short)f2bf(v - bf2f(h));
        }
    }

    float bd[4][4];
    int bm[4][4];
#pragma unroll
    for (int lt = 0; lt < 4; ++lt)
#pragma unroll
        for (int r = 0; r < 4; ++r) { bd[lt][r] = FLT_MAX; bm[lt][r] = 0; }

    // B-fragment base for this lane: code row (n*512 + j16), d-slice kg*8
    const unsigned short* bh_base = ehi + ((size_t)n * NM + j16) * EPAD + kg * 8;
    const unsigned short* bl_base = elo + ((size_t)n * NM + j16) * EPAD + kg * 8;

    // 2 tiles per iteration, pair prefetch (2-deep effective)
    bf16x8 bh0 = *(const bf16x8*)(bh_base);
    bf16x8 bl0 = *(const bf16x8*)(bl_base);
    bf16x8 bh1 = *(const bf16x8*)(bh_base + TSTR);
    bf16x8 bl1 = *(const bf16x8*)(bl_base + TSTR);
    for (int mt = 0; mt < 32; mt += 2) {
        const bf16x8 cbh0 = bh0, cbl0 = bl0, cbh1 = bh1, cbl1 = bl1;
        if (mt < 30) {
            bh0 = *(const bf16x8*)(bh_base + (size_t)(mt + 2) * TSTR);
            bl0 = *(const bf16x8*)(bl_base + (size_t)(mt + 2) * TSTR);
            bh1 = *(const bf16x8*)(bh_base + (size_t)(mt + 3) * TSTR);
            bl1 = *(const bf16x8*)(bl_base + (size_t)(mt + 3) * TSTR);
        }
        {
            const int mloc = mt * 16 + j16;
            const float e2v = se2[mloc];
#pragma unroll
            for (int lt = 0; lt < 4; ++lt) {
                f32x4 c = {0.f, 0.f, 0.f, 0.f};
                c = __builtin_amdgcn_mfma_f32_16x16x32_bf16(ah[lt], cbh0, c, 0, 0, 0);
                c = __builtin_amdgcn_mfma_f32_16x16x32_bf16(al[lt], cbh0, c, 0, 0, 0);
                c = __builtin_amdgcn_mfma_f32_16x16x32_bf16(ah[lt], cbl0, c, 0, 0, 0);
#pragma unroll
                for (int r = 0; r < 4; ++r) {
                    const float dist = fmaf(-2.f, c[r], e2v);
                    if (dist < bd[lt][r]) { bd[lt][r] = dist; bm[lt][r] = mloc; }
                }
            }
        }
        {
            const int mloc = (mt + 1) * 16 + j16;
            const float e2v = se2[mloc];
#pragma unroll
            for (int lt = 0; lt < 4; ++lt) {
                f32x4 c = {0.f, 0.f, 0.f, 0.f};
                c = __builtin_amdgcn_mfma_f32_16x16x32_bf16(ah[lt], cbh1, c, 0, 0, 0);
                c = __builtin_amdgcn_mfma_f32_16x16x32_bf16(al[lt], cbh1, c, 0, 0, 0);
                c = __builtin_amdgcn_mfma_f32_16x16x32_bf16(ah[lt], cbl1, c, 0, 0, 0);
#pragma unroll
                for (int r = 0; r < 4; ++r) {
                    const float dist = fmaf(-2.f, c[r], e2v);
                    if (dist < bd[lt][r]) { bd[lt][r] = dist; bm[lt][r] = mloc; }
                }
            }
        }
    }

    // reduce over the 16 lanes (cols) of each group; tie -> lower m (np.argmin)
#pragma unroll
    for (int lt = 0; lt < 4; ++lt)
#pragma unroll
        for (int r = 0; r < 4; ++r) {
            float d0 = bd[lt][r];
            int m0 = bm[lt][r];
#pragma unroll
            for (int off = 1; off < 16; off <<= 1) {
                const float dn = __shfl_xor(d0, off, 64);
                const int mn = __shfl_xor(m0, off, 64);
                if (dn < d0 || (dn == d0 && mn < m0)) { d0 = dn; m0 = mn; }
            }
            bd[lt][r] = d0;
            bm[lt][r] = m0;
        }
    if (j16 == 0) {
#pragma unroll
        for (int lt = 0; lt < 4; ++lt)
#pragma unroll
            for (int r = 0; r < 4; ++r)
                sidx[w * 64 + lt * 16 + kg * 4 + r] = (unsigned short)bm[lt][r];
    }
    __syncthreads();

    // epilogue: idx write, quantized out, exact fp32 loss
    const unsigned m = sidx[tid];
    idx_out[n * NL + lbase + tid] = (unsigned short)m;
    const float* q = emb + ((size_t)n * NM + m) * ND;
    float* op = out + (size_t)b * NCHW + n * ND * NHW + hw0 + tid;
    float lacc = 0.f;
#pragma unroll
    for (int d0 = 0; d0 < ND; d0 += 4) {
        const float4 qv = *(const float4*)&q[d0];
        float xd, df;
        xd = sx[tid * XPAD + d0 + 0]; op[(d0 + 0) * NHW] = qv.x; df = xd - qv.x; lacc = fmaf(df, df, lacc);
        xd = sx[tid * XPAD + d0 + 1]; op[(d0 + 1) * NHW] = qv.y; df = xd - qv.y; lacc = fmaf(df, df, lacc);
        xd = sx[tid * XPAD + d0 + 2]; op[(d0 + 2) * NHW] = qv.z; df = xd - qv.z; lacc = fmaf(df, df, lacc);
        xd = sx[tid * XPAD + d0 + 3]; op[(d0 + 3) * NHW] = qv.w; df = xd - qv.w; lacc = fmaf(df, df, lacc);
    }
#pragma unroll
    for (int off = 32; off; off >>= 1) lacc += __shfl_down(lacc, off);
    if (lane == 0) red[w] = lacc;
    __syncthreads();
    if (tid == 0)
        atomicAdd(loss_out, (red[0] + red[1] + red[2] + red[3]) * LOSS_SCALE);
}

// ---- K3: counts/dw scatter v3: stage x chunk to LDS (coalesced, no
//      load->atomic dependency chains), then lane=(point,d) accumulate:
//      all 32 d's of a point in parallel, conflict-free LDS banks. ----
__launch_bounds__(512, 1)
__global__ void vq_scatter(const float* __restrict__ x,
                           const unsigned short* __restrict__ idx,
                           float* __restrict__ pdw, float* __restrict__ pcnt,
                           int bpc, int exclusive) {
    __shared__ float sdw[NM * XPAD];      // 67584 B
    __shared__ float scnt[NM];            // 2048 B
    __shared__ float sx[SCHUNK * XPAD];   // 16896 B
    __shared__ unsigned short sm[SCHUNK]; // 256 B   (~86.8 KB total)
    const int n = blockIdx.y;
    const int ch = blockIdx.x; // chunk of bpc batches
    const int tid = threadIdx.x; // 0..511

    for (int i = tid; i < NM * XPAD; i += 512) sdw[i] = 0.f;
    if (tid < NM) scnt[tid] = 0.f;
    __syncthreads();

    const int sd = tid >> 4;          // staging: d row 0..31
    const int si0 = (tid & 15) * 8;   // staging: 8 consecutive points
    const int ad = tid & 31;          // accumulate: d
    const int apr = tid >> 5;         // accumulate: point row 0..15

    for (int bb = 0; bb < bpc; ++bb) {
        const int b = ch * bpc + bb;
        const float* xp = x + (size_t)b * NCHW + n * ND * NHW;
        const unsigned short* ip = idx + n * NL + b * NHW;
        for (int c = 0; c < NHW / SCHUNK; ++c) { // 8 chunks of 128 points
            // phase A: stage chunk (pure loads -> LDS writes)
            {
                const float* src = xp + sd * NHW + c * SCHUNK + si0;
                const float4 v0 = *(const float4*)(src);
                const float4 v1 = *(const float4*)(src + 4);
                float* dst = &sx[si0 * XPAD + sd];
                dst[0 * XPAD] = v0.x; dst[1 * XPAD] = v0.y;
                dst[2 * XPAD] = v0.z; dst[3 * XPAD] = v0.w;
                dst[4 * XPAD] = v1.x; dst[5 * XPAD] = v1.y;
                dst[6 * XPAD] = v1.z; dst[7 * XPAD] = v1.w;
            }
            if (tid < SCHUNK) sm[tid] = ip[c * SCHUNK + tid];
            __syncthreads();
            // phase B: LDS-only accumulate, 16 points x 32 d per iteration
#pragma unroll
            for (int it = 0; it < SCHUNK / 16; ++it) { // 8
                const int p = it * 16 + apr;
                const unsigned m = sm[p];
                atomicAdd(&sdw[m * XPAD + ad], sx[p * XPAD + ad]);
                if (ad == 0) atomicAdd(&scnt[m], 1.0f);
            }
            __syncthreads(); // before next chunk overwrites sx
        }
    }

    const int c = exclusive ? ch : 0;
    float* dwn = pdw + (size_t)c * (NN * NM * ND) + (size_t)n * NM * ND;
    if (exclusive) {
        for (int i = tid; i < NM * ND; i += 512)
            dwn[i] = sdw[(i >> 5) * XPAD + (i & 31)];
        if (tid < NM) pcnt[(size_t)c * (NN * NM) + n * NM + tid] = scnt[tid];
    } else {
        for (int i = tid; i < NM * ND; i += 512)
            atomicAdd(&dwn[i], sdw[(i >> 5) * XPAD + (i & 31)]);
        if (tid < NM) atomicAdd(&pcnt[n * NM + tid], scnt[tid]);
    }
}

// ---- K4a: reduce copies + EMA count update + perplexity ----
__global__ void vq_update_cnt(const float* __restrict__ ema_count,
                              const float* __restrict__ pcnt,
                              float* __restrict__ out_cnt,
                              float* __restrict__ perp_out, int copies) {
    const int n = blockIdx.x;
    const int m = threadIdx.x; // 512
    __shared__ float r1[8], r2[8];
    __shared__ float s_ntot;

    float cnt = 0.f;
    for (int c = 0; c < copies; ++c)
        cnt += pcnt[(size_t)c * (NN * NM) + n * NM + m];

    const float cnew = DECAYF * ema_count[n * NM + m] + OMDF * cnt;
    const float avg = cnt / (float)NL;
    const float pterm = avg * logf(avg + 1e-10f);

    float v1 = cnew, v2 = pterm;
#pragma unroll
    for (int off = 32; off; off >>= 1) {
        v1 += __shfl_down(v1, off);
        v2 += __shfl_down(v2, off);
    }
    if ((m & 63) == 0) { r1[m >> 6] = v1; r2[m >> 6] = v2; }
    __syncthreads();
    if (m == 0) {
        float a = 0.f, bsum = 0.f;
#pragma unroll
        for (int i = 0; i < 8; ++i) { a += r1[i]; bsum += r2[i]; }
        s_ntot = a;
        atomicAdd(perp_out, expf(-bsum));
    }
    __syncthreads();
    const float ntot = s_ntot;
    out_cnt[n * NM + m] = (cnew + EPSF) / (ntot + MEPSF) * ntot;
}

// ---- K4b: reduce copies + EMA weight + embedding_new ----
__global__ void vq_update_w(const float* __restrict__ ema_weight,
                            const float* __restrict__ pdw,
                            const float* __restrict__ out_cnt,
                            float* __restrict__ out_w,
                            float* __restrict__ out_emb, int copies) {
    const int i = blockIdx.x * 512 + threadIdx.x; // 131072
    float dw = 0.f;
    for (int c = 0; c < copies; ++c)
        dw += pdw[(size_t)c * (NN * NM * ND) + i];
    const float wnew = DECAYF * ema_weight[i] + OMDF * dw;
    out_w[i] = wnew;
    out_emb[i] = wnew / out_cnt[i >> 5];
}

extern "C" void kernel_launch(void* const* d_in, const int* in_sizes, int n_in,
                              void* d_out, int out_size, void* d_ws, size_t ws_size,
                              hipStream_t stream) {
    const float* x = (const float*)d_in[0];
    const float* emb = (const float*)d_in[1];
    const float* ema_count = (const float*)d_in[2];
    const float* ema_weight = (const float*)d_in[3];
    float* out = (float*)d_out;
    char* ws = (char*)d_ws;

    // choose partial-copy count from scratch size (ws_size is call-invariant)
    const size_t rest_bytes = 16384 + 327680 + 327680 + 524288; // e2, ehi, elo, idx
    const size_t per_copy = (size_t)(NN * NM + NN * NM * ND) * 4; // 540672
    int copies, bpc;
    if (ws_size >= 32 * per_copy + rest_bytes)      { copies = 32; bpc = 1; }
    else if (ws_size >= 16 * per_copy + rest_bytes) { copies = 16; bpc = 2; }
    else if (ws_size >= 8 * per_copy + rest_bytes)  { copies = 8;  bpc = 4; }
    else                                            { copies = 1;  bpc = 4; }
    const int exclusive = (copies > 1) ? 1 : 0;

    float* pcnt = (float*)ws;                                   // copies * 16384 B
    float* pdw = (float*)(ws + (size_t)copies * NN * NM * 4);   // copies * 524288 B
    char* restp = ws + (size_t)copies * per_copy;
    float* e2 = (float*)restp;
    unsigned short* ehi = (unsigned short*)(restp + 16384);
    unsigned short* elo = (unsigned short*)(restp + 16384 + 327680);
    unsigned short* idxp = (unsigned short*)(restp + 16384 + 655360);

    // zero accumulators only when the flush accumulates atomically;
    // exclusive mode overwrites every cell of every copy.
    if (!exclusive)
        hipMemsetAsync(ws, 0, per_copy, stream);
    hipMemsetAsync(out + OUT_LOSS, 0, 2 * sizeof(float), stream);

    e_prep<<<16, 256, 0, stream>>>(emb, ehi, elo, e2);
    vq_argmin<<<dim3(NL / 256, NN), 256, 0, stream>>>(x, ehi, elo, e2, emb, out, idxp,
                                                      out + OUT_LOSS);
    vq_scatter<<<dim3(NB / bpc, NN), 512, 0, stream>>>(x, idxp, pdw, pcnt, bpc,
                                                       exclusive);
    vq_update_cnt<<<NN, NM, 0, stream>>>(ema_count, pcnt, out + OUT_CNT, out + OUT_PERP,
                                         copies);
    vq_update_w<<<NN * NM * ND / 512, 512, 0, stream>>>(ema_weight, pdw, out + OUT_CNT,
                                                        out + OUT_EMB, out + OUT_W, copies);
}

// Round 12
// 197.223 us; speedup vs baseline: 1.1744x; 1.0431x over previous
//
#include <hip/hip_runtime.h>
#include <cfloat>
#include <cmath>

// Problem constants
#define NB 32           // B
#define NN 8            // N codebooks
#define NM 512          // M codes
#define ND 32           // D dim
#define NHW 1024        // H*W
#define NC 256          // C = N*D
#define NCHW (NC * NHW) // 262144
#define NL (NB * NHW)   // 32768 points per codebook
#define EPAD 40         // padded bf16 row (80 B) for codes
#define XPAD 33         // padded fp32 row in argmin
#define TSTR (16 * EPAD) // shorts per 16-code tile
#define PPAD 1032       // padded point-row for dw staging (bf16)

static constexpr float DECAYF = (float)0.999;
static constexpr float OMDF = (float)(1.0 - 0.999);
static constexpr float EPSF = 1e-5f;
static constexpr float MEPSF = (float)(512.0 * 1e-5);
static constexpr float LOSS_SCALE = (float)(0.25 / 8388608.0);

// Output layout (floats)
#define OUT_LOSS (NB * NC * NHW)         // 8388608
#define OUT_PERP (OUT_LOSS + 1)
#define OUT_EMB (OUT_PERP + 1)
#define OUT_CNT (OUT_EMB + NN * NM * ND)
#define OUT_W (OUT_CNT + NN * NM)

typedef __attribute__((ext_vector_type(8))) short bf16x8;
typedef __attribute__((ext_vector_type(4))) short short4v;
typedef __attribute__((ext_vector_type(4))) float f32x4;

__device__ inline unsigned short f2bf(float f) {
    unsigned u = __builtin_bit_cast(unsigned, f);
    u += 0x7FFFu + ((u >> 16) & 1u);
    return (unsigned short)(u >> 16);
}
__device__ inline float bf2f(unsigned short h) {
    unsigned u = ((unsigned)h) << 16;
    return __builtin_bit_cast(float, u);
}

// ---- K1: embedding prep: bf16 hi/lo split (padded rows) + e2 ----
__global__ void e_prep(const float* __restrict__ emb, unsigned short* __restrict__ ehi,
                       unsigned short* __restrict__ elo, float* __restrict__ e2) {
    const int i = blockIdx.x * 256 + threadIdx.x; // (n*512 + m), 4096 total
    const float* e = emb + i * ND;
    unsigned short* hi = ehi + (size_t)i * EPAD;
    unsigned short* lo = elo + (size_t)i * EPAD;
    float s = 0.f;
#pragma unroll
    for (int d = 0; d < ND; ++d) {
        const float v = e[d];
        s = fmaf(v, v, s);
        const unsigned short h = f2bf(v);
        hi[d] = h;
        lo[d] = f2bf(v - bf2f(h));
    }
    e2[i] = s;
}

// ---- K2: MFMA distances + argmin + quantized output + loss ----
// (unchanged from rounds 9-11 for attribution)
__launch_bounds__(256, 4)
__global__ void vq_argmin(const float* __restrict__ x,
                          const unsigned short* __restrict__ ehi,
                          const unsigned short* __restrict__ elo,
                          const float* __restrict__ e2g,
                          const float* __restrict__ emb,
                          float* __restrict__ out,
                          unsigned short* __restrict__ idx_out,
                          float* __restrict__ loss_out) {
    __shared__ __align__(16) float sx[256 * XPAD];           // 33792 B
    __shared__ float se2[NM];                                // 2048 B
    __shared__ unsigned short sidx[256];
    __shared__ float red[4];

    const int n = blockIdx.y;
    const int lbase = blockIdx.x * 256;
    const int tid = threadIdx.x;
    const int b = lbase >> 10;
    const int hw0 = lbase & (NHW - 1);

    {
        const float* xp = x + (size_t)b * NCHW + n * ND * NHW + hw0 + tid;
#pragma unroll
        for (int d = 0; d < ND; ++d)
            sx[tid * XPAD + d] = xp[d * NHW];
    }
    for (int i = tid; i < NM; i += 256) se2[i] = e2g[n * NM + i];
    __syncthreads();

    const int lane = tid & 63;
    const int w = tid >> 6;
    const int j16 = lane & 15;
    const int kg = lane >> 4;

    bf16x8 ah[4], al[4];
#pragma unroll
    for (int lt = 0; lt < 4; ++lt) {
        const int row = w * 64 + lt * 16 + j16;
        const float* sr = &sx[row * XPAD + kg * 8];
#pragma unroll
        for (int j = 0; j < 8; ++j) {
            const float v = sr[j];
            const unsigned short h = f2bf(v);
            ah[lt][j] = (short)h;
            al[lt][j] = (short)f2bf(v - bf2f(h));
        }
    }

    float bd[4][4];
    int bm[4][4];
#pragma unroll
    for (int lt = 0; lt < 4; ++lt)
#pragma unroll
        for (int r = 0; r < 4; ++r) { bd[lt][r] = FLT_MAX; bm[lt][r] = 0; }

    const unsigned short* bh_base = ehi + ((size_t)n * NM + j16) * EPAD + kg * 8;
    const unsigned short* bl_base = elo + ((size_t)n * NM + j16) * EPAD + kg * 8;

    bf16x8 bh0 = *(const bf16x8*)(bh_base);
    bf16x8 bl0 = *(const bf16x8*)(bl_base);
    bf16x8 bh1 = *(const bf16x8*)(bh_base + TSTR);
    bf16x8 bl1 = *(const bf16x8*)(bl_base + TSTR);
    for (int mt = 0; mt < 32; mt += 2) {
        const bf16x8 cbh0 = bh0, cbl0 = bl0, cbh1 = bh1, cbl1 = bl1;
        if (mt < 30) {
            bh0 = *(const bf16x8*)(bh_base + (size_t)(mt + 2) * TSTR);
            bl0 = *(const bf16x8*)(bl_base + (size_t)(mt + 2) * TSTR);
            bh1 = *(const bf16x8*)(bh_base + (size_t)(mt + 3) * TSTR);
            bl1 = *(const bf16x8*)(bl_base + (size_t)(mt + 3) * TSTR);
        }
        {
            const int mloc = mt * 16 + j16;
            const float e2v = se2[mloc];
#pragma unroll
            for (int lt = 0; lt < 4; ++lt) {
                f32x4 c = {0.f, 0.f, 0.f, 0.f};
                c = __builtin_amdgcn_mfma_f32_16x16x32_bf16(ah[lt], cbh0, c, 0, 0, 0);
                c = __builtin_amdgcn_mfma_f32_16x16x32_bf16(al[lt], cbh0, c, 0, 0, 0);
                c = __builtin_amdgcn_mfma_f32_16x16x32_bf16(ah[lt], cbl0, c, 0, 0, 0);
#pragma unroll
                for (int r = 0; r < 4; ++r) {
                    const float dist = fmaf(-2.f, c[r], e2v);
                    if (dist < bd[lt][r]) { bd[lt][r] = dist; bm[lt][r] = mloc; }
                }
            }
        }
        {
            const int mloc = (mt + 1) * 16 + j16;
            const float e2v = se2[mloc];
#pragma unroll
            for (int lt = 0; lt < 4; ++lt) {
                f32x4 c = {0.f, 0.f, 0.f, 0.f};
                c = __builtin_amdgcn_mfma_f32_16x16x32_bf16(ah[lt], cbh1, c, 0, 0, 0);
                c = __builtin_amdgcn_mfma_f32_16x16x32_bf16(al[lt], cbh1, c, 0, 0, 0);
                c = __builtin_amdgcn_mfma_f32_16x16x32_bf16(ah[lt], cbl1, c, 0, 0, 0);
#pragma unroll
                for (int r = 0; r < 4; ++r) {
                    const float dist = fmaf(-2.f, c[r], e2v);
                    if (dist < bd[lt][r]) { bd[lt][r] = dist; bm[lt][r] = mloc; }
                }
            }
        }
    }

#pragma unroll
    for (int lt = 0; lt < 4; ++lt)
#pragma unroll
        for (int r = 0; r < 4; ++r) {
            float d0 = bd[lt][r];
            int m0 = bm[lt][r];
#pragma unroll
            for (int off = 1; off < 16; off <<= 1) {
                const float dn = __shfl_xor(d0, off, 64);
                const int mn = __shfl_xor(m0, off, 64);
                if (dn < d0 || (dn == d0 && mn < m0)) { d0 = dn; m0 = mn; }
            }
            bd[lt][r] = d0;
            bm[lt][r] = m0;
        }
    if (j16 == 0) {
#pragma unroll
        for (int lt = 0; lt < 4; ++lt)
#pragma unroll
            for (int r = 0; r < 4; ++r)
                sidx[w * 64 + lt * 16 + kg * 4 + r] = (unsigned short)bm[lt][r];
    }
    __syncthreads();

    const unsigned m = sidx[tid];
    idx_out[n * NL + lbase + tid] = (unsigned short)m;
    const float* q = emb + ((size_t)n * NM + m) * ND;
    float* op = out + (size_t)b * NCHW + n * ND * NHW + hw0 + tid;
    float lacc = 0.f;
#pragma unroll
    for (int d0 = 0; d0 < ND; d0 += 4) {
        const float4 qv = *(const float4*)&q[d0];
        float xd, df;
        xd = sx[tid * XPAD + d0 + 0]; op[(d0 + 0) * NHW] = qv.x; df = xd - qv.x; lacc = fmaf(df, df, lacc);
        xd = sx[tid * XPAD + d0 + 1]; op[(d0 + 1) * NHW] = qv.y; df = xd - qv.y; lacc = fmaf(df, df, lacc);
        xd = sx[tid * XPAD + d0 + 2]; op[(d0 + 2) * NHW] = qv.z; df = xd - qv.z; lacc = fmaf(df, df, lacc);
        xd = sx[tid * XPAD + d0 + 3]; op[(d0 + 3) * NHW] = qv.w; df = xd - qv.w; lacc = fmaf(df, df, lacc);
    }
#pragma unroll
    for (int off = 32; off; off >>= 1) lacc += __shfl_down(lacc, off);
    if (lane == 0) red[w] = lacc;
    __syncthreads();
    if (tid == 0)
        atomicAdd(loss_out, (red[0] + red[1] + red[2] + red[3]) * LOSS_SCALE);
}

// ---- K3: dw/counts via MFMA one-hot GEMM. Block = (chunk b, n), 256 thr.
//      C[d][m] = sum_p x[d][p] * onehot[p][m]; counts via all-ones A row.
//      No atomics; exclusive plain-store flush per (copy=b, n). ----
__launch_bounds__(256, 1)
__global__ void vq_dw(const float* __restrict__ x,
                      const unsigned short* __restrict__ idx,
                      float* __restrict__ pdw, float* __restrict__ pcnt,
                      int exclusive, int copy_mask) {
    __shared__ __align__(16) unsigned short sxh[ND * PPAD]; // 66048 B
    __shared__ __align__(16) unsigned short sxl[ND * PPAD]; // 66048 B
    __shared__ __align__(16) unsigned short sidx[NHW];      // 2048 B  (134 KB)

    const int n = blockIdx.y;
    const int ch = blockIdx.x; // == batch b, 32 chunks of 1024 points
    const int tid = threadIdx.x;

    // stage x chunk as bf16 hi/lo, [d][p] layout (matches global layout)
    {
        const float* xp = x + (size_t)ch * NCHW + n * ND * NHW;
        for (int i = tid; i < ND * (NHW / 4); i += 256) {
            const int d = i >> 8;
            const int p4 = (i & 255) << 2;
            const float4 v = *(const float4*)(xp + d * NHW + p4);
            short4v hv, lv;
            {
                const unsigned short h = f2bf(v.x);
                hv[0] = (short)h; lv[0] = (short)f2bf(v.x - bf2f(h));
            }
            {
                const unsigned short h = f2bf(v.y);
                hv[1] = (short)h; lv[1] = (short)f2bf(v.y - bf2f(h));
            }
            {
                const unsigned short h = f2bf(v.z);
                hv[2] = (short)h; lv[2] = (short)f2bf(v.z - bf2f(h));
            }
            {
                const unsigned short h = f2bf(v.w);
                hv[3] = (short)h; lv[3] = (short)f2bf(v.w - bf2f(h));
            }
            *(short4v*)&sxh[d * PPAD + p4] = hv;
            *(short4v*)&sxl[d * PPAD + p4] = lv;
        }
        const unsigned short* ip = idx + n * NL + ch * NHW;
        for (int i = tid; i < NHW; i += 256)
            sidx[i] = ip[i];
    }
    __syncthreads();

    const int lane = tid & 63;
    const int w = tid >> 6;
    const int j16 = lane & 15;   // B col (m) / A row (d)
    const int kg = lane >> 4;    // k-group

    bf16x8 ones = {0, 0, 0, 0, 0, 0, 0, 0};
    if (j16 == 0) {
#pragma unroll
        for (int j = 0; j < 8; ++j) ones[j] = (short)0x3F80;
    }

    const int c = exclusive ? ch : (ch & copy_mask);
    float* dwn = pdw + (size_t)c * (NN * NM * ND) + (size_t)n * NM * ND;
    float* cn = pcnt + (size_t)c * (NN * NM) + n * NM;

    for (int pass = 0; pass < 2; ++pass) {
        const int mtb = w * 8 + pass * 4; // this wave's 4 m-tiles
        f32x4 acc[4][5];
#pragma unroll
        for (int mt = 0; mt < 4; ++mt)
#pragma unroll
            for (int a = 0; a < 5; ++a) acc[mt][a] = (f32x4){0.f, 0.f, 0.f, 0.f};

        for (int ks = 0; ks < 32; ++ks) {
            const int kp = ks * 32 + kg * 8;
            const bf16x8 si = *(const bf16x8*)&sidx[kp];
            const bf16x8 ah0 = *(const bf16x8*)&sxh[j16 * PPAD + kp];
            const bf16x8 ah1 = *(const bf16x8*)&sxh[(j16 + 16) * PPAD + kp];
            const bf16x8 al0 = *(const bf16x8*)&sxl[j16 * PPAD + kp];
            const bf16x8 al1 = *(const bf16x8*)&sxl[(j16 + 16) * PPAD + kp];
#pragma unroll
            for (int mt = 0; mt < 4; ++mt) {
                const short mg = (short)((mtb + mt) * 16 + j16);
                bf16x8 bf;
#pragma unroll
                for (int j = 0; j < 8; ++j)
                    bf[j] = (si[j] == mg) ? (short)0x3F80 : (short)0;
                acc[mt][0] = __builtin_amdgcn_mfma_f32_16x16x32_bf16(ah0, bf, acc[mt][0], 0, 0, 0);
                acc[mt][1] = __builtin_amdgcn_mfma_f32_16x16x32_bf16(ah1, bf, acc[mt][1], 0, 0, 0);
                acc[mt][2] = __builtin_amdgcn_mfma_f32_16x16x32_bf16(al0, bf, acc[mt][2], 0, 0, 0);
                acc[mt][3] = __builtin_amdgcn_mfma_f32_16x16x32_bf16(al1, bf, acc[mt][3], 0, 0, 0);
                acc[mt][4] = __builtin_amdgcn_mfma_f32_16x16x32_bf16(ones, bf, acc[mt][4], 0, 0, 0);
            }
        }

        // flush this pass's 4 m-tiles. C mapping: col=lane&15 (m), row=kg*4+r (d).
#pragma unroll
        for (int mt = 0; mt < 4; ++mt) {
            const int m = (mtb + mt) * 16 + j16;
            float* base = dwn + (size_t)m * ND;
            float4 v0, v1;
            v0.x = acc[mt][0][0] + acc[mt][2][0];
            v0.y = acc[mt][0][1] + acc[mt][2][1];
            v0.z = acc[mt][0][2] + acc[mt][2][2];
            v0.w = acc[mt][0][3] + acc[mt][2][3];
            v1.x = acc[mt][1][0] + acc[mt][3][0];
            v1.y = acc[mt][1][1] + acc[mt][3][1];
            v1.z = acc[mt][1][2] + acc[mt][3][2];
            v1.w = acc[mt][1][3] + acc[mt][3][3];
            if (exclusive) {
                *(float4*)(base + kg * 4) = v0;
                *(float4*)(base + 16 + kg * 4) = v1;
                if (lane < 16) cn[m] = acc[mt][4][0];
            } else {
                atomicAdd(base + kg * 4 + 0, v0.x);
                atomicAdd(base + kg * 4 + 1, v0.y);
                atomicAdd(base + kg * 4 + 2, v0.z);
                atomicAdd(base + kg * 4 + 3, v0.w);
                atomicAdd(base + 16 + kg * 4 + 0, v1.x);
                atomicAdd(base + 16 + kg * 4 + 1, v1.y);
                atomicAdd(base + 16 + kg * 4 + 2, v1.z);
                atomicAdd(base + 16 + kg * 4 + 3, v1.w);
                if (lane < 16) atomicAdd(&cn[m], acc[mt][4][0]);
            }
        }
    }
}

// ---- K4a: reduce copies + EMA count update + perplexity ----
__global__ void vq_update_cnt(const float* __restrict__ ema_count,
                              const float* __restrict__ pcnt,
                              float* __restrict__ out_cnt,
                              float* __restrict__ perp_out, int copies) {
    const int n = blockIdx.x;
    const int m = threadIdx.x; // 512
    __shared__ float r1[8], r2[8];
    __shared__ float s_ntot;

    float cnt = 0.f;
    for (int c = 0; c < copies; ++c)
        cnt += pcnt[(size_t)c * (NN * NM) + n * NM + m];

    const float cnew = DECAYF * ema_count[n * NM + m] + OMDF * cnt;
    const float avg = cnt / (float)NL;
    const float pterm = avg * logf(avg + 1e-10f);

    float v1 = cnew, v2 = pterm;
#pragma unroll
    for (int off = 32; off; off >>= 1) {
        v1 += __shfl_down(v1, off);
        v2 += __shfl_down(v2, off);
    }
    if ((m & 63) == 0) { r1[m >> 6] = v1; r2[m >> 6] = v2; }
    __syncthreads();
    if (m == 0) {
        float a = 0.f, bsum = 0.f;
#pragma unroll
        for (int i = 0; i < 8; ++i) { a += r1[i]; bsum += r2[i]; }
        s_ntot = a;
        atomicAdd(perp_out, expf(-bsum));
    }
    __syncthreads();
    const float ntot = s_ntot;
    out_cnt[n * NM + m] = (cnew + EPSF) / (ntot + MEPSF) * ntot;
}

// ---- K4b: reduce copies + EMA weight + embedding_new ----
__global__ void vq_update_w(const float* __restrict__ ema_weight,
                            const float* __restrict__ pdw,
                            const float* __restrict__ out_cnt,
                            float* __restrict__ out_w,
                            float* __restrict__ out_emb, int copies) {
    const int i = blockIdx.x * 512 + threadIdx.x; // 131072
    float dw = 0.f;
    for (int c = 0; c < copies; ++c)
        dw += pdw[(size_t)c * (NN * NM * ND) + i];
    const float wnew = DECAYF * ema_weight[i] + OMDF * dw;
    out_w[i] = wnew;
    out_emb[i] = wnew / out_cnt[i >> 5];
}

extern "C" void kernel_launch(void* const* d_in, const int* in_sizes, int n_in,
                              void* d_out, int out_size, void* d_ws, size_t ws_size,
                              hipStream_t stream) {
    const float* x = (const float*)d_in[0];
    const float* emb = (const float*)d_in[1];
    const float* ema_count = (const float*)d_in[2];
    const float* ema_weight = (const float*)d_in[3];
    float* out = (float*)d_out;
    char* ws = (char*)d_ws;

    // choose partial-copy count from scratch size (ws_size is call-invariant)
    const size_t rest_bytes = 16384 + 327680 + 327680 + 524288; // e2, ehi, elo, idx
    const size_t per_copy = (size_t)(NN * NM + NN * NM * ND) * 4; // 540672
    int copies;
    if (ws_size >= 32 * per_copy + rest_bytes)      copies = 32;
    else if (ws_size >= 8 * per_copy + rest_bytes)  copies = 8;
    else                                            copies = 1;
    const int exclusive = (copies == 32) ? 1 : 0;

    float* pcnt = (float*)ws;                                   // copies * 16384 B
    float* pdw = (float*)(ws + (size_t)copies * NN * NM * 4);   // copies * 524288 B
    char* restp = ws + (size_t)copies * per_copy;
    float* e2 = (float*)restp;
    unsigned short* ehi = (unsigned short*)(restp + 16384);
    unsigned short* elo = (unsigned short*)(restp + 16384 + 327680);
    unsigned short* idxp = (unsigned short*)(restp + 16384 + 655360);

    // zero partials only when the flush accumulates atomically;
    // exclusive mode overwrites every cell of every copy.
    if (!exclusive)
        hipMemsetAsync(ws, 0, (size_t)copies * per_copy, stream);
    hipMemsetAsync(out + OUT_LOSS, 0, 2 * sizeof(float), stream);

    e_prep<<<16, 256, 0, stream>>>(emb, ehi, elo, e2);
    vq_argmin<<<dim3(NL / 256, NN), 256, 0, stream>>>(x, ehi, elo, e2, emb, out, idxp,
                                                      out + OUT_LOSS);
    vq_dw<<<dim3(NB, NN), 256, 0, stream>>>(x, idxp, pdw, pcnt, exclusive, copies - 1);
    vq_update_cnt<<<NN, NM, 0, stream>>>(ema_count, pcnt, out + OUT_CNT, out + OUT_PERP,
                                         copies);
    vq_update_w<<<NN * NM * ND / 512, 512, 0, stream>>>(ema_weight, pdw, out + OUT_CNT,
                                                        out + OUT_EMB, out + OUT_W, copies);
}